// Round 9
// baseline (159.619 us; speedup 1.0000x reference)
//
#include <hip/hip_runtime.h>
#include <cstddef>

#define EMBED 1024
#define HEADS 16
#define HDIM  64
#define BATCH 2
#define SEQ   2048
#define MTOT  (BATCH*SEQ)

typedef __attribute__((ext_vector_type(8)))  short short8;   // 8 bf16 = 4 VGPRs
typedef __attribute__((ext_vector_type(4)))  float f32x4;    // 16x16 C/D frag
typedef __attribute__((ext_vector_type(16))) float f32x16;   // 32x32 C/D frag

typedef __attribute__((address_space(1))) const unsigned int* gas_u32p;
typedef __attribute__((address_space(3))) unsigned int* las_u32p;

// async global->LDS, 16B per lane; LDS dest = wave-uniform base + lane*16
static __device__ __forceinline__ void gload_lds16(const void* g, void* l) {
    __builtin_amdgcn_global_load_lds((gas_u32p)g, (las_u32p)l, 16, 0, 0);
}

// fp32 -> bf16 round-to-nearest-even
static __device__ __forceinline__ unsigned short f2bf(float x) {
    unsigned u = __builtin_bit_cast(unsigned, x);
    unsigned r = (u + 0x7FFFu + ((u >> 16) & 1u)) >> 16;
    return (unsigned short)r;
}

// pack two fp32 -> one u32 of 2 bf16 (hardware cvt)
static __device__ __forceinline__ unsigned pk_bf16(float lo, float hi) {
    unsigned r;
    asm("v_cvt_pk_bf16_f32 %0, %1, %2" : "=v"(r) : "v"(lo), "v"(hi));
    return r;
}

// swap: a' = {a.lo-lanes | b.lo-lanes}, b' = {a.hi-lanes | b.hi-lanes}
static __device__ __forceinline__ void plane32_swap(unsigned &a, unsigned &b) {
    auto r = __builtin_amdgcn_permlane32_swap((int)a, (int)b, false, false);
    a = (unsigned)r[0];
    b = (unsigned)r[1];
}

static __device__ __forceinline__ f32x16 mfma32(short8 a, short8 b, f32x16 c) {
    return __builtin_amdgcn_mfma_f32_32x32x16_bf16(a, b, c, 0, 0, 0);
}

// ---------------------------------------------------------------------------
// convx: x fp32 -> bf16 (8 elems/thread)
// ---------------------------------------------------------------------------
__global__ __launch_bounds__(256)
void convx(const float* __restrict__ x, unsigned short* __restrict__ xh)
{
    const size_t i = ((size_t)blockIdx.x * 256 + threadIdx.x) * 8;
    float4 a = *(const float4*)(x + i);
    float4 b = *(const float4*)(x + i + 4);
    unsigned short o[8] __attribute__((aligned(16)));
    o[0] = f2bf(a.x); o[1] = f2bf(a.y); o[2] = f2bf(a.z); o[3] = f2bf(a.w);
    o[4] = f2bf(b.x); o[5] = f2bf(b.y); o[6] = f2bf(b.z); o[7] = f2bf(b.w);
    *(uint4*)(xh + i) = *(const uint4*)o;
}

// ---------------------------------------------------------------------------
// convw: {Wq,Wk,Wv,Wo} fp32 -> packed bf16 Wh[sel][1M]
// ---------------------------------------------------------------------------
__global__ __launch_bounds__(256)
void convw(const float* __restrict__ Wq, const float* __restrict__ Wk,
           const float* __restrict__ Wv, const float* __restrict__ Wo,
           unsigned short* __restrict__ Wh)
{
    const int sel = blockIdx.y;
    const float* src = sel == 0 ? Wq : sel == 1 ? Wk : sel == 2 ? Wv : Wo;
    unsigned short* dst = Wh + (size_t)sel * EMBED * EMBED;
    const size_t i = ((size_t)blockIdx.x * 256 + threadIdx.x) * 4;
    float4 a = *(const float4*)(src + i);
    ushort4 o;
    o.x = f2bf(a.x); o.y = f2bf(a.y); o.z = f2bf(a.z); o.w = f2bf(a.w);
    *(ushort4*)(dst + i) = o;
}

// ---------------------------------------------------------------------------
// Fused QKV GEMM (bf16 MFMA), 2-phase double-buffered, plain 2D grid (T1
// reverted — R8 showed it cost +14MB FETCH). LDS tiles stored CHUNK-MAJOR:
// elem = chunk*1024 + row*8 + j  (chunk = 16B k-slice). This is a pure
// source-address permutation (gload_lds dest stays linear) and makes the
// frag ds_read_b128 bank = 4*row mod 32 -> 2-way (free) instead of 8-way.
// V written directly transposed to Vt[b][h][d][s]. Q pre-scaled by
// 0.125*log2(e) so attention uses exp2 directly.
// ---------------------------------------------------------------------------
__global__ __launch_bounds__(256)
void gemm_qkv_bf16(const unsigned short* __restrict__ A,
                   const unsigned short* __restrict__ Wqh,
                   const unsigned short* __restrict__ Wkh,
                   const unsigned short* __restrict__ Wvh,
                   const float* __restrict__ bq,
                   const float* __restrict__ bk,
                   const float* __restrict__ bv,
                   unsigned short* __restrict__ Qb,
                   unsigned short* __restrict__ Kb,
                   unsigned short* __restrict__ Vt)
{
    __shared__ short As[2][4 * 1024];   // [buf][chunk][row][8]
    __shared__ short Bs[2][4 * 1024];

    const int tid  = threadIdx.x;
    const int lane = tid & 63;
    const int w    = tid >> 6;
    const int c    = lane & 15;
    const int g    = lane >> 4;
    const int wr   = w >> 1;
    const int wc   = w & 1;

    const int m0   = blockIdx.y * 128;
    const int bxn  = blockIdx.x;
    const int wsel = bxn >> 3;
    const int n0   = (bxn & 7) * 128;

    const unsigned short* W = (wsel == 0) ? Wqh : (wsel == 1) ? Wkh : Wvh;
    const float* bias       = (wsel == 0) ? bq  : (wsel == 1) ? bk  : bv;

    // staging: slot = (w*2+i)*64 + lane, chunk = slot>>7, row = slot&127.
    // LDS elem offset = slot*8 (linear in lane); source decodes chunk-major.
    const int slot0 = (w * 2) * 64 + lane;
    const int slot1 = slot0 + 64;
    const int row0 = slot0 & 127, ch0 = slot0 >> 7;
    const int row1 = slot1 & 127, ch1 = slot1 >> 7;
    const unsigned short* aS0 = A + (size_t)(m0 + row0) * EMBED + ch0 * 8;
    const unsigned short* aS1 = A + (size_t)(m0 + row1) * EMBED + ch1 * 8;
    const unsigned short* bS0 = W + (size_t)(n0 + row0) * EMBED + ch0 * 8;
    const unsigned short* bS1 = W + (size_t)(n0 + row1) * EMBED + ch1 * 8;
    const int d0 = (w * 2) * 512;
    const int d1 = (w * 2 + 1) * 512;

    #define GSTAGE(bb)                                 \
        do {                                           \
            gload_lds16(aS0, &As[bb][d0]);             \
            gload_lds16(aS1, &As[bb][d1]);             \
            gload_lds16(bS0, &Bs[bb][d0]);             \
            gload_lds16(bS1, &Bs[bb][d1]);             \
            aS0 += 32; aS1 += 32; bS0 += 32; bS1 += 32;\
        } while (0)

    f32x4 acc[4][4] = {};

    GSTAGE(0);
    __syncthreads();

    for (int t = 0; t < EMBED / 32; ++t) {
        const int cb = t & 1;
        if (t < EMBED / 32 - 1) GSTAGE(cb ^ 1);        // prefetch overlaps compute

        short8 af[4], bf[4];
        #pragma unroll
        for (int mi = 0; mi < 4; ++mi)
            af[mi] = *(const short8*)&As[cb][g * 1024 + (wr * 64 + mi * 16 + c) * 8];
        #pragma unroll
        for (int ni = 0; ni < 4; ++ni)
            bf[ni] = *(const short8*)&Bs[cb][g * 1024 + (wc * 64 + ni * 16 + c) * 8];
        __builtin_amdgcn_s_setprio(1);
        #pragma unroll
        for (int mi = 0; mi < 4; ++mi)
            #pragma unroll
            for (int ni = 0; ni < 4; ++ni)
                acc[mi][ni] = __builtin_amdgcn_mfma_f32_16x16x32_bf16(
                    af[mi], bf[ni], acc[mi][ni], 0, 0, 0);
        __builtin_amdgcn_s_setprio(0);

        __syncthreads();                               // drain prefetch; buf handoff
    }
    #undef GSTAGE

    if (wsel == 2) {
        #pragma unroll
        for (int mi = 0; mi < 4; ++mi) {
            const int m  = m0 + wr * 64 + mi * 16 + g * 4;
            const int bb = m >> 11;
            const int ss = m & (SEQ - 1);
            #pragma unroll
            for (int ni = 0; ni < 4; ++ni) {
                const int col = n0 + wc * 64 + ni * 16 + c;
                const int hh = col >> 6, dd = col & 63;
                const float bi_ = bias[col];
                ushort4 o;
                o.x = f2bf(acc[mi][ni][0] + bi_);
                o.y = f2bf(acc[mi][ni][1] + bi_);
                o.z = f2bf(acc[mi][ni][2] + bi_);
                o.w = f2bf(acc[mi][ni][3] + bi_);
                *(ushort4*)&Vt[((size_t)((bb * HEADS + hh) * HDIM) + dd) * SEQ + ss] = o;
            }
        }
    } else {
        unsigned short* Out = (wsel == 0) ? Qb : Kb;
        // Q scale folds softmax 1/8 AND log2(e) so flash uses exp2 directly
        const float oscale  = (wsel == 0) ? 0.180336880f : 1.0f;
        #pragma unroll
        for (int mi = 0; mi < 4; ++mi)
            #pragma unroll
            for (int r = 0; r < 4; ++r) {
                const int m = m0 + wr * 64 + mi * 16 + g * 4 + r;
                #pragma unroll
                for (int ni = 0; ni < 4; ++ni) {
                    const int col = n0 + wc * 64 + ni * 16 + c;
                    Out[(size_t)m * EMBED + col] =
                        f2bf((acc[mi][ni][r] + bias[col]) * oscale);
                }
            }
    }
}

// ---------------------------------------------------------------------------
// Output GEMM: BM=BN=128, 2-phase double-buffered, chunk-major LDS, 2D grid.
// ---------------------------------------------------------------------------
__global__ __launch_bounds__(256)
void gemm_o_bf16(const unsigned short* __restrict__ A,
                 const unsigned short* __restrict__ Woh,
                 const float* __restrict__ bo,
                 float* __restrict__ C)
{
    __shared__ short As[2][4 * 1024];
    __shared__ short Bs[2][4 * 1024];

    const int tid  = threadIdx.x;
    const int lane = tid & 63;
    const int w    = tid >> 6;
    const int c    = lane & 15;
    const int g    = lane >> 4;
    const int wr   = w >> 1;
    const int wc   = w & 1;

    const int m0 = blockIdx.y * 128;
    const int n0 = blockIdx.x * 128;

    const int slot0 = (w * 2) * 64 + lane;
    const int slot1 = slot0 + 64;
    const int row0 = slot0 & 127, ch0 = slot0 >> 7;
    const int row1 = slot1 & 127, ch1 = slot1 >> 7;
    const unsigned short* aS0 = A   + (size_t)(m0 + row0) * EMBED + ch0 * 8;
    const unsigned short* aS1 = A   + (size_t)(m0 + row1) * EMBED + ch1 * 8;
    const unsigned short* bS0 = Woh + (size_t)(n0 + row0) * EMBED + ch0 * 8;
    const unsigned short* bS1 = Woh + (size_t)(n0 + row1) * EMBED + ch1 * 8;
    const int d0 = (w * 2) * 512;
    const int d1 = (w * 2 + 1) * 512;

    #define GSTAGE(bb)                                 \
        do {                                           \
            gload_lds16(aS0, &As[bb][d0]);             \
            gload_lds16(aS1, &As[bb][d1]);             \
            gload_lds16(bS0, &Bs[bb][d0]);             \
            gload_lds16(bS1, &Bs[bb][d1]);             \
            aS0 += 32; aS1 += 32; bS0 += 32; bS1 += 32;\
        } while (0)

    f32x4 acc[4][4] = {};

    GSTAGE(0);
    __syncthreads();

    for (int t = 0; t < EMBED / 32; ++t) {
        const int cb = t & 1;
        if (t < EMBED / 32 - 1) GSTAGE(cb ^ 1);

        short8 af[4], bf[4];
        #pragma unroll
        for (int mi = 0; mi < 4; ++mi)
            af[mi] = *(const short8*)&As[cb][g * 1024 + (wr * 64 + mi * 16 + c) * 8];
        #pragma unroll
        for (int ni = 0; ni < 4; ++ni)
            bf[ni] = *(const short8*)&Bs[cb][g * 1024 + (wc * 64 + ni * 16 + c) * 8];
        __builtin_amdgcn_s_setprio(1);
        #pragma unroll
        for (int mi = 0; mi < 4; ++mi)
            #pragma unroll
            for (int ni = 0; ni < 4; ++ni)
                acc[mi][ni] = __builtin_amdgcn_mfma_f32_16x16x32_bf16(
                    af[mi], bf[ni], acc[mi][ni], 0, 0, 0);
        __builtin_amdgcn_s_setprio(0);

        __syncthreads();
    }
    #undef GSTAGE

    #pragma unroll
    for (int mi = 0; mi < 4; ++mi)
        #pragma unroll
        for (int r = 0; r < 4; ++r) {
            const int m = m0 + wr * 64 + mi * 16 + g * 4 + r;
            #pragma unroll
            for (int ni = 0; ni < 4; ++ni) {
                const int col = n0 + wc * 64 + ni * 16 + c;
                C[(size_t)m * EMBED + col] = acc[mi][ni][r] + bo[col];
            }
        }
}

// ---------------------------------------------------------------------------
// MFMA flash attention v5 (unchanged; proven):
// fixed-base softmax via exp2, in-register P, kv-split-2, 2-phase staging.
// ---------------------------------------------------------------------------
__global__ __launch_bounds__(512, 4)
void flash_attn_mfma5(const unsigned short* __restrict__ Qb,
                      const unsigned short* __restrict__ Kb,
                      const unsigned short* __restrict__ Vt,
                      unsigned short* __restrict__ O)
{
    __shared__ short KT[2][2][64 * 64];   // [half][buf][kv][d]  (swizzled chunks)
    __shared__ short VT[2][2][64 * 64];   // [half][buf][d][kv]

    const int tid  = threadIdx.x;
    const int lane = tid & 63;
    const int w    = tid >> 6;            // 0..7
    const int qt   = w & 3;               // q subtile
    const int half = w >> 2;              // kv half
    const int l31  = lane & 31;
    const int hi   = lane >> 5;
    const int q0   = blockIdx.x * 128 + qt * 32;
    const int h    = blockIdx.y;
    const int b    = blockIdx.z;

    // persistent Q B-frags: qf[kc] holds Q[q=l31][d = kc*16 + hi*8 + j]
    short8 qf[4];
    {
        const unsigned short* qrow =
            Qb + (size_t)(b * SEQ + q0 + l31) * EMBED + h * HDIM + hi * 8;
        #pragma unroll
        for (int kc = 0; kc < 4; ++kc)
            qf[kc] = *(const short8*)(qrow + kc * 16);
    }

    // staging: tile tb = w>>1 (0=K_lo,1=V_lo,2=K_hi,3=V_hi), ssub = w&1.
    const int tb     = w >> 1;
    const int sthalf = tb >> 1;
    const int stV    = tb & 1;
    const int ssub   = w & 1;
    const int strow  = ssub * 32 + (lane >> 3);
    const int ch     = (lane & 7) ^ (strow & 7);
    const unsigned short* kS =
        Kb + (size_t)(b * SEQ + sthalf * (SEQ / 2) + strow) * EMBED + h * HDIM + ch * 8;
    const unsigned short* vS =
        Vt + ((size_t)((b * HEADS + h) * HDIM) + strow) * SEQ + sthalf * (SEQ / 2) + ch * 8;

    f32x16 acc[2] = {};
    float l_run = 0.f;

    #define STAGE(kt2, bb)                                                    \
        do {                                                                  \
            if (stV == 0) {                                                   \
                const unsigned short* src = kS + (size_t)(kt2) * 64 * EMBED;  \
                short* kd = &KT[sthalf][bb][ssub * 2048];                     \
                _Pragma("unroll")                                             \
                for (int it = 0; it < 4; ++it)                                \
                    gload_lds16(src + (size_t)it * 8 * EMBED, kd + it * 512); \
            } else {                                                          \
                const unsigned short* src = vS + (kt2) * 64;                  \
                short* vd = &VT[sthalf][bb][ssub * 2048];                     \
                _Pragma("unroll")                                             \
                for (int it = 0; it < 4; ++it)                                \
                    gload_lds16(src + (size_t)it * 8 * SEQ, vd + it * 512);   \
            }                                                                 \
        } while (0)

    STAGE(0, 0);
    __syncthreads();

    for (int kt = 0; kt < SEQ / 2 / 64; ++kt) {
        const int bi = kt & 1;
        if (kt < SEQ / 2 / 64 - 1) STAGE(kt + 1, bi ^ 1);

        const short* kb_ = &KT[half][bi][0];
        const short* vb_ = &VT[half][bi][0];

        // ---- QK^T (C: col=l31=q, row=kv via qr formula)
        f32x16 s[2] = {};
        __builtin_amdgcn_s_setprio(1);
        #pragma unroll
        for (int t = 0; t < 2; ++t) {
            const int row = t * 32 + l31;
            const int rm  = l31 & 7;
            #pragma unroll
            for (int kc = 0; kc < 4; ++kc) {
                short8 ka = *(const short8*)&kb_[row * 64 + (((2 * kc + hi) ^ rm) * 8)];
                s[t] = mfma32(ka, qf[kc], s[t]);
            }
        }
        __builtin_amdgcn_s_setprio(0);

        // ---- P = exp2(s'), row-sum (fixed-base softmax: no max machinery)
        float rs = 0.f;
        #pragma unroll
        for (int t = 0; t < 2; ++t)
            #pragma unroll
            for (int r = 0; r < 16; ++r) {
                float pv = __builtin_amdgcn_exp2f(s[t][r]);
                s[t][r] = pv;
                rs += pv;
            }
        rs += __shfl_xor(rs, 32, 64);
        l_run += rs;

        // ---- P -> A-frags in-register (cvt_pk + permlane32_swap)
        short8 pf[2][2];
        #pragma unroll
        for (int t = 0; t < 2; ++t)
            #pragma unroll
            for (int kc = 0; kc < 2; ++kc) {
                unsigned A0 = pk_bf16(s[t][8 * kc + 0], s[t][8 * kc + 1]);
                unsigned A1 = pk_bf16(s[t][8 * kc + 2], s[t][8 * kc + 3]);
                unsigned B0 = pk_bf16(s[t][8 * kc + 4], s[t][8 * kc + 5]);
                unsigned B1 = pk_bf16(s[t][8 * kc + 6], s[t][8 * kc + 7]);
                plane32_swap(A0, B0);
                plane32_swap(A1, B1);
                uint4 fw = make_uint4(A0, A1, B0, B1);
                pf[t][kc] = __builtin_bit_cast(short8, fw);
            }

        // ---- PV
        __builtin_amdgcn_s_setprio(1);
        #pragma unroll
        for (int dt = 0; dt < 2; ++dt) {
            const int row = dt * 32 + l31;
            const int rm  = l31 & 7;
            #pragma unroll
            for (int t = 0; t < 2; ++t)
                #pragma unroll
                for (int kc = 0; kc < 2; ++kc) {
                    short8 vf = *(const short8*)
                        &vb_[row * 64 + (((4 * t + 2 * kc + hi) ^ rm) * 8)];
                    acc[dt] = mfma32(pf[t][kc], vf, acc[dt]);
                }
        }
        __builtin_amdgcn_s_setprio(0);

        __syncthreads();
    }
    #undef STAGE

    // ---- merge kv-halves: O = (O_lo + O_hi) / (l_lo + l_hi)  (exact fp32)
    float* mrgf = (float*)&KT[0][0][0];   // 4 pairs x 32q x 64d fp32 = 32KB
    float* mlbf = (float*)&VT[0][0][0];   // 4 pairs x 32q l-values
    if (half == 1) {
        #pragma unroll
        for (int dt = 0; dt < 2; ++dt)
            #pragma unroll
            for (int r = 0; r < 16; ++r) {
                const int qr = (r & 3) + 8 * (r >> 2) + 4 * hi;
                mrgf[qt * 2048 + qr * 64 + dt * 32 + l31] = acc[dt][r];
            }
        if (lane < 32)
            mlbf[qt * 32 + lane] = l_run;
    }
    __syncthreads();
    if (half == 0) {
        const float lo  = mlbf[qt * 32 + l31];
        const float inv = 1.f / (l_run + lo);
        #pragma unroll
        for (int r = 0; r < 16; ++r) {
            const int qr = (r & 3) + 8 * (r >> 2) + 4 * hi;
            float invr = __shfl(inv, qr, 64);
            #pragma unroll
            for (int dt = 0; dt < 2; ++dt) {
                float oh  = mrgf[qt * 2048 + qr * 64 + dt * 32 + l31];
                float val = (acc[dt][r] + oh) * invr;
                O[(size_t)(b * SEQ + q0 + qr) * EMBED + h * HDIM + dt * 32 + l31]
                    = f2bf(val);
            }
        }
    }
}

// ---------------------------------------------------------------------------
extern "C" void kernel_launch(void* const* d_in, const int* in_sizes, int n_in,
                              void* d_out, int out_size, void* d_ws, size_t ws_size,
                              hipStream_t stream)
{
    const float* x  = (const float*)d_in[0];
    const float* Wq = (const float*)d_in[1];
    const float* bq = (const float*)d_in[2];
    const float* Wk = (const float*)d_in[3];
    const float* bk = (const float*)d_in[4];
    const float* Wv = (const float*)d_in[5];
    const float* bv = (const float*)d_in[6];
    const float* Wo = (const float*)d_in[7];
    const float* bo = (const float*)d_in[8];
    float* out = (float*)d_out;

    const size_t ME = (size_t)MTOT * EMBED;
    unsigned short* xh   = (unsigned short*)d_ws;     // 8 MB each
    unsigned short* Qb   = xh   + ME;
    unsigned short* Kb   = Qb   + ME;
    unsigned short* Vt   = Kb   + ME;                 // [b][h][d][s]
    unsigned short* attn = Vt   + ME;
    unsigned short* Wh   = attn + ME;                 // 4 x 2 MB packed

    dim3 blk(256);

    convx<<<dim3(MTOT * EMBED / 2048), blk, 0, stream>>>(x, xh);
    convw<<<dim3(EMBED * EMBED / 1024, 4), blk, 0, stream>>>(Wq, Wk, Wv, Wo, Wh);

    gemm_qkv_bf16<<<dim3(24, MTOT / 128), blk, 0, stream>>>(
        xh, Wh, Wh + (size_t)EMBED * EMBED, Wh + 2 * (size_t)EMBED * EMBED,
        bq, bk, bv, Qb, Kb, Vt);

    flash_attn_mfma5<<<dim3(SEQ / 128, HEADS, BATCH), dim3(512), 0, stream>>>(
        Qb, Kb, Vt, attn);

    gemm_o_bf16<<<dim3(EMBED / 128, MTOT / 128), blk, 0, stream>>>(
        attn, Wh + 3 * (size_t)EMBED * EMBED, bo, out);
}

// Round 10
// 136.869 us; speedup vs baseline: 1.1662x; 1.1662x over previous
//
#include <hip/hip_runtime.h>
#include <cstddef>

#define EMBED 1024
#define HEADS 16
#define HDIM  64
#define BATCH 2
#define SEQ   2048
#define MTOT  (BATCH*SEQ)

typedef __attribute__((ext_vector_type(8)))  short short8;   // 8 bf16 = 4 VGPRs
typedef __attribute__((ext_vector_type(4)))  float f32x4;    // 16x16 C/D frag
typedef __attribute__((ext_vector_type(16))) float f32x16;   // 32x32 C/D frag

typedef __attribute__((address_space(1))) const unsigned int* gas_u32p;
typedef __attribute__((address_space(3))) unsigned int* las_u32p;

// async global->LDS, 16B per lane; LDS dest = wave-uniform base + lane*16
static __device__ __forceinline__ void gload_lds16(const void* g, void* l) {
    __builtin_amdgcn_global_load_lds((gas_u32p)g, (las_u32p)l, 16, 0, 0);
}

// fp32 -> bf16 round-to-nearest-even
static __device__ __forceinline__ unsigned short f2bf(float x) {
    unsigned u = __builtin_bit_cast(unsigned, x);
    unsigned r = (u + 0x7FFFu + ((u >> 16) & 1u)) >> 16;
    return (unsigned short)r;
}

// pack two fp32 -> one u32 of 2 bf16 (hardware cvt)
static __device__ __forceinline__ unsigned pk_bf16(float lo, float hi) {
    unsigned r;
    asm("v_cvt_pk_bf16_f32 %0, %1, %2" : "=v"(r) : "v"(lo), "v"(hi));
    return r;
}

// swap: a' = {a.lo-lanes | b.lo-lanes}, b' = {a.hi-lanes | b.hi-lanes}
static __device__ __forceinline__ void plane32_swap(unsigned &a, unsigned &b) {
    auto r = __builtin_amdgcn_permlane32_swap((int)a, (int)b, false, false);
    a = (unsigned)r[0];
    b = (unsigned)r[1];
}

static __device__ __forceinline__ f32x16 mfma32(short8 a, short8 b, f32x16 c) {
    return __builtin_amdgcn_mfma_f32_32x32x16_bf16(a, b, c, 0, 0, 0);
}

// ---------------------------------------------------------------------------
// convx: x fp32 -> bf16 (8 elems/thread)
// ---------------------------------------------------------------------------
__global__ __launch_bounds__(256)
void convx(const float* __restrict__ x, unsigned short* __restrict__ xh)
{
    const size_t i = ((size_t)blockIdx.x * 256 + threadIdx.x) * 8;
    float4 a = *(const float4*)(x + i);
    float4 b = *(const float4*)(x + i + 4);
    unsigned short o[8] __attribute__((aligned(16)));
    o[0] = f2bf(a.x); o[1] = f2bf(a.y); o[2] = f2bf(a.z); o[3] = f2bf(a.w);
    o[4] = f2bf(b.x); o[5] = f2bf(b.y); o[6] = f2bf(b.z); o[7] = f2bf(b.w);
    *(uint4*)(xh + i) = *(const uint4*)o;
}

// ---------------------------------------------------------------------------
// convw: {Wq,Wk,Wv,Wo} fp32 -> packed bf16 Wh[sel][1M]
// ---------------------------------------------------------------------------
__global__ __launch_bounds__(256)
void convw(const float* __restrict__ Wq, const float* __restrict__ Wk,
           const float* __restrict__ Wv, const float* __restrict__ Wo,
           unsigned short* __restrict__ Wh)
{
    const int sel = blockIdx.y;
    const float* src = sel == 0 ? Wq : sel == 1 ? Wk : sel == 2 ? Wv : Wo;
    unsigned short* dst = Wh + (size_t)sel * EMBED * EMBED;
    const size_t i = ((size_t)blockIdx.x * 256 + threadIdx.x) * 4;
    float4 a = *(const float4*)(src + i);
    ushort4 o;
    o.x = f2bf(a.x); o.y = f2bf(a.y); o.z = f2bf(a.z); o.w = f2bf(a.w);
    *(ushort4*)(dst + i) = o;
}

// ---------------------------------------------------------------------------
// Fused QKV GEMM v2: 256x256 tile, BK=64, 8 waves (2M x 4N), 4-phase pipeline
// with raw s_barrier + single vmcnt(0) per K-iter (loads span barriers).
// LDS [row][chunk] linear; source-XOR swizzle ch^=(row&7) (flash-proven:
// 2-way banks on ds_read_b128, global coalescing preserved). T5 setprio.
// Grid (12,16): bx>>2 selects {Q,K,V}, (bx&3)*256 = n0. 1 block/CU (128KB).
// V written directly transposed to Vt[b][h][d][s]; Q pre-scaled 0.125*log2e.
// ---------------------------------------------------------------------------
__global__ __launch_bounds__(512, 2)
void gemm_qkv_8ph(const unsigned short* __restrict__ A,
                  const unsigned short* __restrict__ Wqh,
                  const unsigned short* __restrict__ Wkh,
                  const unsigned short* __restrict__ Wvh,
                  const float* __restrict__ bq,
                  const float* __restrict__ bk,
                  const float* __restrict__ bv,
                  unsigned short* __restrict__ Qb,
                  unsigned short* __restrict__ Kb,
                  unsigned short* __restrict__ Vt)
{
    __shared__ short AL[2][256 * 64];   // [buf][row][chunk*8]  64KB
    __shared__ short BL[2][256 * 64];   // 64KB

    const int tid  = threadIdx.x;
    const int lane = tid & 63;
    const int w    = tid >> 6;        // 0..7
    const int wm   = w >> 2;          // 0..1 : rows wm*128..+128
    const int wn   = w & 3;           // 0..3 : cols wn*64..+64
    const int c    = lane & 15;
    const int g    = lane >> 4;

    const int m0   = blockIdx.y * 256;
    const int bx   = blockIdx.x;      // 0..11
    const int wsel = bx >> 2;
    const int n0   = (bx & 3) * 256;

    const unsigned short* W = (wsel == 0) ? Wqh : (wsel == 1) ? Wkh : Wvh;
    const float* bias       = (wsel == 0) ? bq  : (wsel == 1) ? bk  : bv;

    // staging geometry: half-tile = 128 rows x 8 chunks = 1024 slots;
    // instr j covers slots j*512+tid. row = slot>>3, src chunk = (slot&7)^(row&7).
    const int s0  = tid;
    const int s1  = 512 + tid;
    const int r0  = s0 >> 3;                   // 0..63
    const int r1  = s1 >> 3;                   // 64..127
    const int cs0 = (s0 & 7) ^ (r0 & 7);
    const int cs1 = (s1 & 7) ^ (r1 & 7);
    const int db0 = (0 * 512 + w * 64) * 8;    // wave-uniform LDS elem bases
    const int db1 = (1 * 512 + w * 64) * 8;

    // phase p stages: p=0,1 -> A half p; p=2,3 -> B half p-2.
    #define STG(bb, p, kofs)                                                   \
        do {                                                                   \
            const unsigned short* gbase = ((p) < 2) ? A : W;                   \
            const int mn0 = ((p) < 2) ? m0 : n0;                               \
            short* ldsb = ((p) < 2) ? &AL[bb][0] : &BL[bb][0];                 \
            const int hf = (p) & 1;                                           \
            gload_lds16(gbase + (size_t)(mn0 + hf * 128 + r0) * EMBED          \
                              + (kofs) + cs0 * 8,                             \
                        ldsb + hf * 8192 + db0);                              \
            gload_lds16(gbase + (size_t)(mn0 + hf * 128 + r1) * EMBED          \
                              + (kofs) + cs1 * 8,                             \
                        ldsb + hf * 8192 + db1);                              \
        } while (0)

    f32x4 acc[4][4][2] = {};   // [quadrant p][mi][ni]

    // prologue: stage tile 0 fully, drain, barrier
    STG(0, 0, 0); STG(0, 1, 0); STG(0, 2, 0); STG(0, 3, 0);
    asm volatile("s_waitcnt vmcnt(0)" ::: "memory");
    __builtin_amdgcn_s_barrier();

    for (int i = 0; i < 16; ++i) {
        const int pi = i & 1;
        const int kn = (i + 1) * 64;
        #pragma unroll
        for (int p = 0; p < 4; ++p) {
            if (i < 15) STG(pi ^ 1, p, kn);    // prefetch next tile, 1 half/phase

            // frag ds_reads for quadrant p of tile i (buf pi)
            const short* Ab = &AL[pi][0];
            const short* Bb = &BL[pi][0];
            short8 af[2][4], bf[2][2];
            #pragma unroll
            for (int ks = 0; ks < 2; ++ks) {
                #pragma unroll
                for (int mi = 0; mi < 4; ++mi) {
                    const int row = wm * 128 + (p >> 1) * 64 + mi * 16 + c;
                    const int chn = (ks * 4 + g) ^ (c & 7);
                    af[ks][mi] = *(const short8*)&Ab[row * 64 + chn * 8];
                }
                #pragma unroll
                for (int ni = 0; ni < 2; ++ni) {
                    const int row = wn * 64 + (p & 1) * 32 + ni * 16 + c;
                    const int chn = (ks * 4 + g) ^ (c & 7);
                    bf[ks][ni] = *(const short8*)&Bb[row * 64 + chn * 8];
                }
            }

            __builtin_amdgcn_s_barrier();      // align waves: loads issued, MFMA next

            __builtin_amdgcn_s_setprio(1);
            #pragma unroll
            for (int mi = 0; mi < 4; ++mi)
                #pragma unroll
                for (int ni = 0; ni < 2; ++ni)
                    #pragma unroll
                    for (int ks = 0; ks < 2; ++ks)
                        acc[p][mi][ni] = __builtin_amdgcn_mfma_f32_16x16x32_bf16(
                            af[ks][mi], bf[ks][ni], acc[p][mi][ni], 0, 0, 0);
            __builtin_amdgcn_s_setprio(0);

            if (p == 3)                         // ONLY drain point: next tile landed
                asm volatile("s_waitcnt vmcnt(0)" ::: "memory");
            __builtin_amdgcn_s_barrier();
        }
    }
    #undef STG

    // epilogue
    if (wsel == 2) {
        #pragma unroll
        for (int p = 0; p < 4; ++p)
            #pragma unroll
            for (int mi = 0; mi < 4; ++mi) {
                const int m  = m0 + wm * 128 + (p >> 1) * 64 + mi * 16 + g * 4;
                const int bb = m >> 11;
                const int ss = m & (SEQ - 1);
                #pragma unroll
                for (int ni = 0; ni < 2; ++ni) {
                    const int col = n0 + wn * 64 + (p & 1) * 32 + ni * 16 + c;
                    const int hh = col >> 6, dd = col & 63;
                    const float bi_ = bias[col];
                    ushort4 o;
                    o.x = f2bf(acc[p][mi][ni][0] + bi_);
                    o.y = f2bf(acc[p][mi][ni][1] + bi_);
                    o.z = f2bf(acc[p][mi][ni][2] + bi_);
                    o.w = f2bf(acc[p][mi][ni][3] + bi_);
                    *(ushort4*)&Vt[((size_t)((bb * HEADS + hh) * HDIM) + dd) * SEQ + ss] = o;
                }
            }
    } else {
        unsigned short* Out = (wsel == 0) ? Qb : Kb;
        const float oscale  = (wsel == 0) ? 0.180336880f : 1.0f;  // 0.125*log2(e)
        #pragma unroll
        for (int p = 0; p < 4; ++p)
            #pragma unroll
            for (int mi = 0; mi < 4; ++mi)
                #pragma unroll
                for (int r = 0; r < 4; ++r) {
                    const int m = m0 + wm * 128 + (p >> 1) * 64 + mi * 16 + g * 4 + r;
                    #pragma unroll
                    for (int ni = 0; ni < 2; ++ni) {
                        const int col = n0 + wn * 64 + (p & 1) * 32 + ni * 16 + c;
                        Out[(size_t)m * EMBED + col] =
                            f2bf((acc[p][mi][ni][r] + bias[col]) * oscale);
                    }
                }
    }
}

// ---------------------------------------------------------------------------
// Output GEMM: restored R7 version (proven ~14us). BM=BN=128, single-buffer.
// ---------------------------------------------------------------------------
__global__ __launch_bounds__(256)
void gemm_o_bf16(const unsigned short* __restrict__ A,
                 const unsigned short* __restrict__ Woh,
                 const float* __restrict__ bo,
                 float* __restrict__ C)
{
    __shared__ short As[128 * 32];
    __shared__ short Bs[128 * 32];

    const int tid  = threadIdx.x;
    const int lane = tid & 63;
    const int w    = tid >> 6;
    const int c    = lane & 15;
    const int g    = lane >> 4;
    const int wr   = w >> 1;
    const int wc   = w & 1;

    const int m0 = blockIdx.y * 128;
    const int n0 = blockIdx.x * 128;

    f32x4 acc[4][4] = {};

    for (int k0 = 0; k0 < EMBED; k0 += 32) {
        __syncthreads();
        #pragma unroll
        for (int i = 0; i < 2; ++i) {
            int s   = (w * 2 + i) * 64 + lane;
            int row = s >> 2;
            int k8  = (s & 3) * 8;
            gload_lds16(A + (size_t)(m0 + row) * EMBED + k0 + k8,
                        As + (size_t)(w * 2 + i) * 512);
            gload_lds16(Woh + (size_t)(n0 + row) * EMBED + k0 + k8,
                        Bs + (size_t)(w * 2 + i) * 512);
        }
        __syncthreads();

        short8 af[4], bf[4];
        #pragma unroll
        for (int mi = 0; mi < 4; ++mi)
            af[mi] = *(const short8*)&As[(wr * 64 + mi * 16 + c) * 32 + g * 8];
        #pragma unroll
        for (int ni = 0; ni < 4; ++ni)
            bf[ni] = *(const short8*)&Bs[(wc * 64 + ni * 16 + c) * 32 + g * 8];
        __builtin_amdgcn_s_setprio(1);
        #pragma unroll
        for (int mi = 0; mi < 4; ++mi)
            #pragma unroll
            for (int ni = 0; ni < 4; ++ni)
                acc[mi][ni] = __builtin_amdgcn_mfma_f32_16x16x32_bf16(
                    af[mi], bf[ni], acc[mi][ni], 0, 0, 0);
        __builtin_amdgcn_s_setprio(0);
    }

    #pragma unroll
    for (int mi = 0; mi < 4; ++mi)
        #pragma unroll
        for (int r = 0; r < 4; ++r) {
            const int m = m0 + wr * 64 + mi * 16 + g * 4 + r;
            #pragma unroll
            for (int ni = 0; ni < 4; ++ni) {
                const int col = n0 + wc * 64 + ni * 16 + c;
                C[(size_t)m * EMBED + col] = acc[mi][ni][r] + bo[col];
            }
        }
}

// ---------------------------------------------------------------------------
// MFMA flash attention v5 (unchanged from R7; proven):
// fixed-base softmax via exp2, in-register P, kv-split-2, 2-phase staging.
// ---------------------------------------------------------------------------
__global__ __launch_bounds__(512, 4)
void flash_attn_mfma5(const unsigned short* __restrict__ Qb,
                      const unsigned short* __restrict__ Kb,
                      const unsigned short* __restrict__ Vt,
                      unsigned short* __restrict__ O)
{
    __shared__ short KT[2][2][64 * 64];   // [half][buf][kv][d]  (swizzled chunks)
    __shared__ short VT[2][2][64 * 64];   // [half][buf][d][kv]

    const int tid  = threadIdx.x;
    const int lane = tid & 63;
    const int w    = tid >> 6;            // 0..7
    const int qt   = w & 3;               // q subtile
    const int half = w >> 2;              // kv half
    const int l31  = lane & 31;
    const int hi   = lane >> 5;
    const int q0   = blockIdx.x * 128 + qt * 32;
    const int h    = blockIdx.y;
    const int b    = blockIdx.z;

    // persistent Q B-frags: qf[kc] holds Q[q=l31][d = kc*16 + hi*8 + j]
    short8 qf[4];
    {
        const unsigned short* qrow =
            Qb + (size_t)(b * SEQ + q0 + l31) * EMBED + h * HDIM + hi * 8;
        #pragma unroll
        for (int kc = 0; kc < 4; ++kc)
            qf[kc] = *(const short8*)(qrow + kc * 16);
    }

    // staging: tile tb = w>>1 (0=K_lo,1=V_lo,2=K_hi,3=V_hi), ssub = w&1.
    const int tb     = w >> 1;
    const int sthalf = tb >> 1;
    const int stV    = tb & 1;
    const int ssub   = w & 1;
    const int strow  = ssub * 32 + (lane >> 3);
    const int ch     = (lane & 7) ^ (strow & 7);
    const unsigned short* kS =
        Kb + (size_t)(b * SEQ + sthalf * (SEQ / 2) + strow) * EMBED + h * HDIM + ch * 8;
    const unsigned short* vS =
        Vt + ((size_t)((b * HEADS + h) * HDIM) + strow) * SEQ + sthalf * (SEQ / 2) + ch * 8;

    f32x16 acc[2] = {};
    float l_run = 0.f;

    #define STAGE(kt2, bb)                                                    \
        do {                                                                  \
            if (stV == 0) {                                                   \
                const unsigned short* src = kS + (size_t)(kt2) * 64 * EMBED;  \
                short* kd = &KT[sthalf][bb][ssub * 2048];                     \
                _Pragma("unroll")                                             \
                for (int it = 0; it < 4; ++it)                                \
                    gload_lds16(src + (size_t)it * 8 * EMBED, kd + it * 512); \
            } else {                                                          \
                const unsigned short* src = vS + (kt2) * 64;                  \
                short* vd = &VT[sthalf][bb][ssub * 2048];                     \
                _Pragma("unroll")                                             \
                for (int it = 0; it < 4; ++it)                                \
                    gload_lds16(src + (size_t)it * 8 * SEQ, vd + it * 512);   \
            }                                                                 \
        } while (0)

    STAGE(0, 0);
    __syncthreads();

    for (int kt = 0; kt < SEQ / 2 / 64; ++kt) {
        const int bi = kt & 1;
        if (kt < SEQ / 2 / 64 - 1) STAGE(kt + 1, bi ^ 1);

        const short* kb_ = &KT[half][bi][0];
        const short* vb_ = &VT[half][bi][0];

        // ---- QK^T (C: col=l31=q, row=kv via qr formula)
        f32x16 s[2] = {};
        __builtin_amdgcn_s_setprio(1);
        #pragma unroll
        for (int t = 0; t < 2; ++t) {
            const int row = t * 32 + l31;
            const int rm  = l31 & 7;
            #pragma unroll
            for (int kc = 0; kc < 4; ++kc) {
                short8 ka = *(const short8*)&kb_[row * 64 + (((2 * kc + hi) ^ rm) * 8)];
                s[t] = mfma32(ka, qf[kc], s[t]);
            }
        }
        __builtin_amdgcn_s_setprio(0);

        // ---- P = exp2(s'), row-sum (fixed-base softmax: no max machinery)
        float rs = 0.f;
        #pragma unroll
        for (int t = 0; t < 2; ++t)
            #pragma unroll
            for (int r = 0; r < 16; ++r) {
                float pv = __builtin_amdgcn_exp2f(s[t][r]);
                s[t][r] = pv;
                rs += pv;
            }
        rs += __shfl_xor(rs, 32, 64);
        l_run += rs;

        // ---- P -> A-frags in-register (cvt_pk + permlane32_swap)
        short8 pf[2][2];
        #pragma unroll
        for (int t = 0; t < 2; ++t)
            #pragma unroll
            for (int kc = 0; kc < 2; ++kc) {
                unsigned A0 = pk_bf16(s[t][8 * kc + 0], s[t][8 * kc + 1]);
                unsigned A1 = pk_bf16(s[t][8 * kc + 2], s[t][8 * kc + 3]);
                unsigned B0 = pk_bf16(s[t][8 * kc + 4], s[t][8 * kc + 5]);
                unsigned B1 = pk_bf16(s[t][8 * kc + 6], s[t][8 * kc + 7]);
                plane32_swap(A0, B0);
                plane32_swap(A1, B1);
                uint4 fw = make_uint4(A0, A1, B0, B1);
                pf[t][kc] = __builtin_bit_cast(short8, fw);
            }

        // ---- PV
        __builtin_amdgcn_s_setprio(1);
        #pragma unroll
        for (int dt = 0; dt < 2; ++dt) {
            const int row = dt * 32 + l31;
            const int rm  = l31 & 7;
            #pragma unroll
            for (int t = 0; t < 2; ++t)
                #pragma unroll
                for (int kc = 0; kc < 2; ++kc) {
                    short8 vf = *(const short8*)
                        &vb_[row * 64 + (((4 * t + 2 * kc + hi) ^ rm) * 8)];
                    acc[dt] = mfma32(pf[t][kc], vf, acc[dt]);
                }
        }
        __builtin_amdgcn_s_setprio(0);

        __syncthreads();
    }
    #undef STAGE

    // ---- merge kv-halves: O = (O_lo + O_hi) / (l_lo + l_hi)  (exact fp32)
    float* mrgf = (float*)&KT[0][0][0];   // 4 pairs x 32q x 64d fp32 = 32KB
    float* mlbf = (float*)&VT[0][0][0];   // 4 pairs x 32q l-values
    if (half == 1) {
        #pragma unroll
        for (int dt = 0; dt < 2; ++dt)
            #pragma unroll
            for (int r = 0; r < 16; ++r) {
                const int qr = (r & 3) + 8 * (r >> 2) + 4 * hi;
                mrgf[qt * 2048 + qr * 64 + dt * 32 + l31] = acc[dt][r];
            }
        if (lane < 32)
            mlbf[qt * 32 + lane] = l_run;
    }
    __syncthreads();
    if (half == 0) {
        const float lo  = mlbf[qt * 32 + l31];
        const float inv = 1.f / (l_run + lo);
        #pragma unroll
        for (int r = 0; r < 16; ++r) {
            const int qr = (r & 3) + 8 * (r >> 2) + 4 * hi;
            float invr = __shfl(inv, qr, 64);
            #pragma unroll
            for (int dt = 0; dt < 2; ++dt) {
                float oh  = mrgf[qt * 2048 + qr * 64 + dt * 32 + l31];
                float val = (acc[dt][r] + oh) * invr;
                O[(size_t)(b * SEQ + q0 + qr) * EMBED + h * HDIM + dt * 32 + l31]
                    = f2bf(val);
            }
        }
    }
}

// ---------------------------------------------------------------------------
extern "C" void kernel_launch(void* const* d_in, const int* in_sizes, int n_in,
                              void* d_out, int out_size, void* d_ws, size_t ws_size,
                              hipStream_t stream)
{
    const float* x  = (const float*)d_in[0];
    const float* Wq = (const float*)d_in[1];
    const float* bq = (const float*)d_in[2];
    const float* Wk = (const float*)d_in[3];
    const float* bk = (const float*)d_in[4];
    const float* Wv = (const float*)d_in[5];
    const float* bv = (const float*)d_in[6];
    const float* Wo = (const float*)d_in[7];
    const float* bo = (const float*)d_in[8];
    float* out = (float*)d_out;

    const size_t ME = (size_t)MTOT * EMBED;
    unsigned short* xh   = (unsigned short*)d_ws;     // 8 MB each
    unsigned short* Qb   = xh   + ME;
    unsigned short* Kb   = Qb   + ME;
    unsigned short* Vt   = Kb   + ME;                 // [b][h][d][s]
    unsigned short* attn = Vt   + ME;
    unsigned short* Wh   = attn + ME;                 // 4 x 2 MB packed

    dim3 blk(256);

    convx<<<dim3(MTOT * EMBED / 2048), blk, 0, stream>>>(x, xh);
    convw<<<dim3(EMBED * EMBED / 1024, 4), blk, 0, stream>>>(Wq, Wk, Wv, Wo, Wh);

    gemm_qkv_8ph<<<dim3(12, MTOT / 256), dim3(512), 0, stream>>>(
        xh, Wh, Wh + (size_t)EMBED * EMBED, Wh + 2 * (size_t)EMBED * EMBED,
        bq, bk, bv, Qb, Kb, Vt);

    flash_attn_mfma5<<<dim3(SEQ / 128, HEADS, BATCH), dim3(512), 0, stream>>>(
        Qb, Kb, Vt, attn);

    gemm_o_bf16<<<dim3(EMBED / 128, MTOT / 128), blk, 0, stream>>>(
        attn, Wh + 3 * (size_t)EMBED * EMBED, bo, out);
}

// Round 11
// 134.090 us; speedup vs baseline: 1.1904x; 1.0207x over previous
//
#include <hip/hip_runtime.h>
#include <cstddef>

#define EMBED 1024
#define HEADS 16
#define HDIM  64
#define BATCH 2
#define SEQ   2048
#define MTOT  (BATCH*SEQ)

typedef __attribute__((ext_vector_type(8)))  short short8;   // 8 bf16 = 4 VGPRs
typedef __attribute__((ext_vector_type(4)))  float f32x4;    // 16x16 C/D frag
typedef __attribute__((ext_vector_type(16))) float f32x16;   // 32x32 C/D frag

typedef __attribute__((address_space(1))) const unsigned int* gas_u32p;
typedef __attribute__((address_space(3))) unsigned int* las_u32p;

// async global->LDS, 16B per lane; LDS dest = wave-uniform base + lane*16
static __device__ __forceinline__ void gload_lds16(const void* g, void* l) {
    __builtin_amdgcn_global_load_lds((gas_u32p)g, (las_u32p)l, 16, 0, 0);
}

// fp32 -> bf16 round-to-nearest-even
static __device__ __forceinline__ unsigned short f2bf(float x) {
    unsigned u = __builtin_bit_cast(unsigned, x);
    unsigned r = (u + 0x7FFFu + ((u >> 16) & 1u)) >> 16;
    return (unsigned short)r;
}

// pack two fp32 -> one u32 of 2 bf16 (hardware cvt)
static __device__ __forceinline__ unsigned pk_bf16(float lo, float hi) {
    unsigned r;
    asm("v_cvt_pk_bf16_f32 %0, %1, %2" : "=v"(r) : "v"(lo), "v"(hi));
    return r;
}

// swap: a' = {a.lo-lanes | b.lo-lanes}, b' = {a.hi-lanes | b.hi-lanes}
static __device__ __forceinline__ void plane32_swap(unsigned &a, unsigned &b) {
    auto r = __builtin_amdgcn_permlane32_swap((int)a, (int)b, false, false);
    a = (unsigned)r[0];
    b = (unsigned)r[1];
}

static __device__ __forceinline__ f32x16 mfma32(short8 a, short8 b, f32x16 c) {
    return __builtin_amdgcn_mfma_f32_32x32x16_bf16(a, b, c, 0, 0, 0);
}

// ---------------------------------------------------------------------------
// convx: x fp32 -> bf16 (8 elems/thread)
// ---------------------------------------------------------------------------
__global__ __launch_bounds__(256)
void convx(const float* __restrict__ x, unsigned short* __restrict__ xh)
{
    const size_t i = ((size_t)blockIdx.x * 256 + threadIdx.x) * 8;
    float4 a = *(const float4*)(x + i);
    float4 b = *(const float4*)(x + i + 4);
    unsigned short o[8] __attribute__((aligned(16)));
    o[0] = f2bf(a.x); o[1] = f2bf(a.y); o[2] = f2bf(a.z); o[3] = f2bf(a.w);
    o[4] = f2bf(b.x); o[5] = f2bf(b.y); o[6] = f2bf(b.z); o[7] = f2bf(b.w);
    *(uint4*)(xh + i) = *(const uint4*)o;
}

// ---------------------------------------------------------------------------
// convw: {Wq,Wk,Wv,Wo} fp32 -> packed bf16 Wh[sel][1M]
// ---------------------------------------------------------------------------
__global__ __launch_bounds__(256)
void convw(const float* __restrict__ Wq, const float* __restrict__ Wk,
           const float* __restrict__ Wv, const float* __restrict__ Wo,
           unsigned short* __restrict__ Wh)
{
    const int sel = blockIdx.y;
    const float* src = sel == 0 ? Wq : sel == 1 ? Wk : sel == 2 ? Wv : Wo;
    unsigned short* dst = Wh + (size_t)sel * EMBED * EMBED;
    const size_t i = ((size_t)blockIdx.x * 256 + threadIdx.x) * 4;
    float4 a = *(const float4*)(src + i);
    ushort4 o;
    o.x = f2bf(a.x); o.y = f2bf(a.y); o.z = f2bf(a.z); o.w = f2bf(a.w);
    *(ushort4*)(dst + i) = o;
}

// ---------------------------------------------------------------------------
// Fused QKV GEMM (bf16 MFMA): R7 structure + double-buffer ONLY (isolated
// experiment: R8 minus T1). Plain 2D grid, row-major LDS [128][32], 2-phase
// loop: prefetch(t+1) -> ds_read+MFMA(t) -> one barrier. V written directly
// transposed to Vt[b][h][d][s]. Q pre-scaled by 0.125*log2(e).
// ---------------------------------------------------------------------------
__global__ __launch_bounds__(256)
void gemm_qkv_bf16(const unsigned short* __restrict__ A,
                   const unsigned short* __restrict__ Wqh,
                   const unsigned short* __restrict__ Wkh,
                   const unsigned short* __restrict__ Wvh,
                   const float* __restrict__ bq,
                   const float* __restrict__ bk,
                   const float* __restrict__ bv,
                   unsigned short* __restrict__ Qb,
                   unsigned short* __restrict__ Kb,
                   unsigned short* __restrict__ Vt)
{
    __shared__ short As[2][128 * 32];
    __shared__ short Bs[2][128 * 32];

    const int tid  = threadIdx.x;
    const int lane = tid & 63;
    const int w    = tid >> 6;
    const int c    = lane & 15;
    const int g    = lane >> 4;
    const int wr   = w >> 1;
    const int wc   = w & 1;

    const int m0   = blockIdx.y * 128;
    const int bxn  = blockIdx.x;
    const int wsel = bxn >> 3;
    const int n0   = (bxn & 7) * 128;

    const unsigned short* W = (wsel == 0) ? Wqh : (wsel == 1) ? Wkh : Wvh;
    const float* bias       = (wsel == 0) ? bq  : (wsel == 1) ? bk  : bv;

    // per-thread staging source pointers (advance 32 elems per K-step)
    const int srow = (w * 2) * 16 + (lane >> 2);     // row for i=0 slot
    const int sk8  = (lane & 3) * 8;
    const unsigned short* aS0 = A + (size_t)(m0 + srow) * EMBED + sk8;
    const unsigned short* aS1 = A + (size_t)(m0 + srow + 16) * EMBED + sk8;
    const unsigned short* bS0 = W + (size_t)(n0 + srow) * EMBED + sk8;
    const unsigned short* bS1 = W + (size_t)(n0 + srow + 16) * EMBED + sk8;
    const int d0 = (w * 2) * 512;
    const int d1 = (w * 2 + 1) * 512;

    #define GSTAGE(bb)                                 \
        do {                                           \
            gload_lds16(aS0, &As[bb][d0]);             \
            gload_lds16(aS1, &As[bb][d1]);             \
            gload_lds16(bS0, &Bs[bb][d0]);             \
            gload_lds16(bS1, &Bs[bb][d1]);             \
            aS0 += 32; aS1 += 32; bS0 += 32; bS1 += 32;\
        } while (0)

    f32x4 acc[4][4] = {};

    GSTAGE(0);
    __syncthreads();

    for (int t = 0; t < EMBED / 32; ++t) {
        const int cb = t & 1;
        if (t < EMBED / 32 - 1) GSTAGE(cb ^ 1);        // prefetch overlaps compute

        short8 af[4], bf[4];
        #pragma unroll
        for (int mi = 0; mi < 4; ++mi)
            af[mi] = *(const short8*)&As[cb][(wr * 64 + mi * 16 + c) * 32 + g * 8];
        #pragma unroll
        for (int ni = 0; ni < 4; ++ni)
            bf[ni] = *(const short8*)&Bs[cb][(wc * 64 + ni * 16 + c) * 32 + g * 8];
        __builtin_amdgcn_s_setprio(1);
        #pragma unroll
        for (int mi = 0; mi < 4; ++mi)
            #pragma unroll
            for (int ni = 0; ni < 4; ++ni)
                acc[mi][ni] = __builtin_amdgcn_mfma_f32_16x16x32_bf16(
                    af[mi], bf[ni], acc[mi][ni], 0, 0, 0);
        __builtin_amdgcn_s_setprio(0);

        __syncthreads();                               // drain prefetch; buf handoff
    }
    #undef GSTAGE

    if (wsel == 2) {
        #pragma unroll
        for (int mi = 0; mi < 4; ++mi) {
            const int m  = m0 + wr * 64 + mi * 16 + g * 4;
            const int bb = m >> 11;
            const int ss = m & (SEQ - 1);
            #pragma unroll
            for (int ni = 0; ni < 4; ++ni) {
                const int col = n0 + wc * 64 + ni * 16 + c;
                const int hh = col >> 6, dd = col & 63;
                const float bi_ = bias[col];
                ushort4 o;
                o.x = f2bf(acc[mi][ni][0] + bi_);
                o.y = f2bf(acc[mi][ni][1] + bi_);
                o.z = f2bf(acc[mi][ni][2] + bi_);
                o.w = f2bf(acc[mi][ni][3] + bi_);
                *(ushort4*)&Vt[((size_t)((bb * HEADS + hh) * HDIM) + dd) * SEQ + ss] = o;
            }
        }
    } else {
        unsigned short* Out = (wsel == 0) ? Qb : Kb;
        // Q scale folds softmax 1/8 AND log2(e) so flash uses exp2 directly
        const float oscale  = (wsel == 0) ? 0.180336880f : 1.0f;
        #pragma unroll
        for (int mi = 0; mi < 4; ++mi)
            #pragma unroll
            for (int r = 0; r < 4; ++r) {
                const int m = m0 + wr * 64 + mi * 16 + g * 4 + r;
                #pragma unroll
                for (int ni = 0; ni < 4; ++ni) {
                    const int col = n0 + wc * 64 + ni * 16 + c;
                    Out[(size_t)m * EMBED + col] =
                        f2bf((acc[mi][ni][r] + bias[col]) * oscale);
                }
            }
    }
}

// ---------------------------------------------------------------------------
// Output GEMM: R7-proven single-buffer, BM=BN=128.
// ---------------------------------------------------------------------------
__global__ __launch_bounds__(256)
void gemm_o_bf16(const unsigned short* __restrict__ A,
                 const unsigned short* __restrict__ Woh,
                 const float* __restrict__ bo,
                 float* __restrict__ C)
{
    __shared__ short As[128 * 32];
    __shared__ short Bs[128 * 32];

    const int tid  = threadIdx.x;
    const int lane = tid & 63;
    const int w    = tid >> 6;
    const int c    = lane & 15;
    const int g    = lane >> 4;
    const int wr   = w >> 1;
    const int wc   = w & 1;

    const int m0 = blockIdx.y * 128;
    const int n0 = blockIdx.x * 128;

    f32x4 acc[4][4] = {};

    for (int k0 = 0; k0 < EMBED; k0 += 32) {
        __syncthreads();
        #pragma unroll
        for (int i = 0; i < 2; ++i) {
            int s   = (w * 2 + i) * 64 + lane;
            int row = s >> 2;
            int k8  = (s & 3) * 8;
            gload_lds16(A + (size_t)(m0 + row) * EMBED + k0 + k8,
                        As + (size_t)(w * 2 + i) * 512);
            gload_lds16(Woh + (size_t)(n0 + row) * EMBED + k0 + k8,
                        Bs + (size_t)(w * 2 + i) * 512);
        }
        __syncthreads();

        short8 af[4], bf[4];
        #pragma unroll
        for (int mi = 0; mi < 4; ++mi)
            af[mi] = *(const short8*)&As[(wr * 64 + mi * 16 + c) * 32 + g * 8];
        #pragma unroll
        for (int ni = 0; ni < 4; ++ni)
            bf[ni] = *(const short8*)&Bs[(wc * 64 + ni * 16 + c) * 32 + g * 8];
        __builtin_amdgcn_s_setprio(1);
        #pragma unroll
        for (int mi = 0; mi < 4; ++mi)
            #pragma unroll
            for (int ni = 0; ni < 4; ++ni)
                acc[mi][ni] = __builtin_amdgcn_mfma_f32_16x16x32_bf16(
                    af[mi], bf[ni], acc[mi][ni], 0, 0, 0);
        __builtin_amdgcn_s_setprio(0);
    }

    #pragma unroll
    for (int mi = 0; mi < 4; ++mi)
        #pragma unroll
        for (int r = 0; r < 4; ++r) {
            const int m = m0 + wr * 64 + mi * 16 + g * 4 + r;
            #pragma unroll
            for (int ni = 0; ni < 4; ++ni) {
                const int col = n0 + wc * 64 + ni * 16 + c;
                C[(size_t)m * EMBED + col] = acc[mi][ni][r] + bo[col];
            }
        }
}

// ---------------------------------------------------------------------------
// MFMA flash attention v5 (unchanged; proven):
// fixed-base softmax via exp2, in-register P, kv-split-2, 2-phase staging.
// ---------------------------------------------------------------------------
__global__ __launch_bounds__(512, 4)
void flash_attn_mfma5(const unsigned short* __restrict__ Qb,
                      const unsigned short* __restrict__ Kb,
                      const unsigned short* __restrict__ Vt,
                      unsigned short* __restrict__ O)
{
    __shared__ short KT[2][2][64 * 64];   // [half][buf][kv][d]  (swizzled chunks)
    __shared__ short VT[2][2][64 * 64];   // [half][buf][d][kv]

    const int tid  = threadIdx.x;
    const int lane = tid & 63;
    const int w    = tid >> 6;            // 0..7
    const int qt   = w & 3;               // q subtile
    const int half = w >> 2;              // kv half
    const int l31  = lane & 31;
    const int hi   = lane >> 5;
    const int q0   = blockIdx.x * 128 + qt * 32;
    const int h    = blockIdx.y;
    const int b    = blockIdx.z;

    // persistent Q B-frags: qf[kc] holds Q[q=l31][d = kc*16 + hi*8 + j]
    short8 qf[4];
    {
        const unsigned short* qrow =
            Qb + (size_t)(b * SEQ + q0 + l31) * EMBED + h * HDIM + hi * 8;
        #pragma unroll
        for (int kc = 0; kc < 4; ++kc)
            qf[kc] = *(const short8*)(qrow + kc * 16);
    }

    // staging: tile tb = w>>1 (0=K_lo,1=V_lo,2=K_hi,3=V_hi), ssub = w&1.
    const int tb     = w >> 1;
    const int sthalf = tb >> 1;
    const int stV    = tb & 1;
    const int ssub   = w & 1;
    const int strow  = ssub * 32 + (lane >> 3);
    const int ch     = (lane & 7) ^ (strow & 7);
    const unsigned short* kS =
        Kb + (size_t)(b * SEQ + sthalf * (SEQ / 2) + strow) * EMBED + h * HDIM + ch * 8;
    const unsigned short* vS =
        Vt + ((size_t)((b * HEADS + h) * HDIM) + strow) * SEQ + sthalf * (SEQ / 2) + ch * 8;

    f32x16 acc[2] = {};
    float l_run = 0.f;

    #define STAGE(kt2, bb)                                                    \
        do {                                                                  \
            if (stV == 0) {                                                   \
                const unsigned short* src = kS + (size_t)(kt2) * 64 * EMBED;  \
                short* kd = &KT[sthalf][bb][ssub * 2048];                     \
                _Pragma("unroll")                                             \
                for (int it = 0; it < 4; ++it)                                \
                    gload_lds16(src + (size_t)it * 8 * EMBED, kd + it * 512); \
            } else {                                                          \
                const unsigned short* src = vS + (kt2) * 64;                  \
                short* vd = &VT[sthalf][bb][ssub * 2048];                     \
                _Pragma("unroll")                                             \
                for (int it = 0; it < 4; ++it)                                \
                    gload_lds16(src + (size_t)it * 8 * SEQ, vd + it * 512);   \
            }                                                                 \
        } while (0)

    STAGE(0, 0);
    __syncthreads();

    for (int kt = 0; kt < SEQ / 2 / 64; ++kt) {
        const int bi = kt & 1;
        if (kt < SEQ / 2 / 64 - 1) STAGE(kt + 1, bi ^ 1);

        const short* kb_ = &KT[half][bi][0];
        const short* vb_ = &VT[half][bi][0];

        // ---- QK^T (C: col=l31=q, row=kv via qr formula)
        f32x16 s[2] = {};
        __builtin_amdgcn_s_setprio(1);
        #pragma unroll
        for (int t = 0; t < 2; ++t) {
            const int row = t * 32 + l31;
            const int rm  = l31 & 7;
            #pragma unroll
            for (int kc = 0; kc < 4; ++kc) {
                short8 ka = *(const short8*)&kb_[row * 64 + (((2 * kc + hi) ^ rm) * 8)];
                s[t] = mfma32(ka, qf[kc], s[t]);
            }
        }
        __builtin_amdgcn_s_setprio(0);

        // ---- P = exp2(s'), row-sum (fixed-base softmax: no max machinery)
        float rs = 0.f;
        #pragma unroll
        for (int t = 0; t < 2; ++t)
            #pragma unroll
            for (int r = 0; r < 16; ++r) {
                float pv = __builtin_amdgcn_exp2f(s[t][r]);
                s[t][r] = pv;
                rs += pv;
            }
        rs += __shfl_xor(rs, 32, 64);
        l_run += rs;

        // ---- P -> A-frags in-register (cvt_pk + permlane32_swap)
        short8 pf[2][2];
        #pragma unroll
        for (int t = 0; t < 2; ++t)
            #pragma unroll
            for (int kc = 0; kc < 2; ++kc) {
                unsigned A0 = pk_bf16(s[t][8 * kc + 0], s[t][8 * kc + 1]);
                unsigned A1 = pk_bf16(s[t][8 * kc + 2], s[t][8 * kc + 3]);
                unsigned B0 = pk_bf16(s[t][8 * kc + 4], s[t][8 * kc + 5]);
                unsigned B1 = pk_bf16(s[t][8 * kc + 6], s[t][8 * kc + 7]);
                plane32_swap(A0, B0);
                plane32_swap(A1, B1);
                uint4 fw = make_uint4(A0, A1, B0, B1);
                pf[t][kc] = __builtin_bit_cast(short8, fw);
            }

        // ---- PV
        __builtin_amdgcn_s_setprio(1);
        #pragma unroll
        for (int dt = 0; dt < 2; ++dt) {
            const int row = dt * 32 + l31;
            const int rm  = l31 & 7;
            #pragma unroll
            for (int t = 0; t < 2; ++t)
                #pragma unroll
                for (int kc = 0; kc < 2; ++kc) {
                    short8 vf = *(const short8*)
                        &vb_[row * 64 + (((4 * t + 2 * kc + hi) ^ rm) * 8)];
                    acc[dt] = mfma32(pf[t][kc], vf, acc[dt]);
                }
        }
        __builtin_amdgcn_s_setprio(0);

        __syncthreads();
    }
    #undef STAGE

    // ---- merge kv-halves: O = (O_lo + O_hi) / (l_lo + l_hi)  (exact fp32)
    float* mrgf = (float*)&KT[0][0][0];   // 4 pairs x 32q x 64d fp32 = 32KB
    float* mlbf = (float*)&VT[0][0][0];   // 4 pairs x 32q l-values
    if (half == 1) {
        #pragma unroll
        for (int dt = 0; dt < 2; ++dt)
            #pragma unroll
            for (int r = 0; r < 16; ++r) {
                const int qr = (r & 3) + 8 * (r >> 2) + 4 * hi;
                mrgf[qt * 2048 + qr * 64 + dt * 32 + l31] = acc[dt][r];
            }
        if (lane < 32)
            mlbf[qt * 32 + lane] = l_run;
    }
    __syncthreads();
    if (half == 0) {
        const float lo  = mlbf[qt * 32 + l31];
        const float inv = 1.f / (l_run + lo);
        #pragma unroll
        for (int r = 0; r < 16; ++r) {
            const int qr = (r & 3) + 8 * (r >> 2) + 4 * hi;
            float invr = __shfl(inv, qr, 64);
            #pragma unroll
            for (int dt = 0; dt < 2; ++dt) {
                float oh  = mrgf[qt * 2048 + qr * 64 + dt * 32 + l31];
                float val = (acc[dt][r] + oh) * invr;
                O[(size_t)(b * SEQ + q0 + qr) * EMBED + h * HDIM + dt * 32 + l31]
                    = f2bf(val);
            }
        }
    }
}

// ---------------------------------------------------------------------------
extern "C" void kernel_launch(void* const* d_in, const int* in_sizes, int n_in,
                              void* d_out, int out_size, void* d_ws, size_t ws_size,
                              hipStream_t stream)
{
    const float* x  = (const float*)d_in[0];
    const float* Wq = (const float*)d_in[1];
    const float* bq = (const float*)d_in[2];
    const float* Wk = (const float*)d_in[3];
    const float* bk = (const float*)d_in[4];
    const float* Wv = (const float*)d_in[5];
    const float* bv = (const float*)d_in[6];
    const float* Wo = (const float*)d_in[7];
    const float* bo = (const float*)d_in[8];
    float* out = (float*)d_out;

    const size_t ME = (size_t)MTOT * EMBED;
    unsigned short* xh   = (unsigned short*)d_ws;     // 8 MB each
    unsigned short* Qb   = xh   + ME;
    unsigned short* Kb   = Qb   + ME;
    unsigned short* Vt   = Kb   + ME;                 // [b][h][d][s]
    unsigned short* attn = Vt   + ME;
    unsigned short* Wh   = attn + ME;                 // 4 x 2 MB packed

    dim3 blk(256);

    convx<<<dim3(MTOT * EMBED / 2048), blk, 0, stream>>>(x, xh);
    convw<<<dim3(EMBED * EMBED / 1024, 4), blk, 0, stream>>>(Wq, Wk, Wv, Wo, Wh);

    gemm_qkv_bf16<<<dim3(24, MTOT / 128), blk, 0, stream>>>(
        xh, Wh, Wh + (size_t)EMBED * EMBED, Wh + 2 * (size_t)EMBED * EMBED,
        bq, bk, bv, Qb, Kb, Vt);

    flash_attn_mfma5<<<dim3(SEQ / 128, HEADS, BATCH), dim3(512), 0, stream>>>(
        Qb, Kb, Vt, attn);

    gemm_o_bf16<<<dim3(EMBED / 128, MTOT / 128), blk, 0, stream>>>(
        attn, Wh + 3 * (size_t)EMBED * EMBED, bo, out);
}

// Round 12
// 117.909 us; speedup vs baseline: 1.3537x; 1.1372x over previous
//
#include <hip/hip_runtime.h>
#include <cstddef>

#define EMBED 1024
#define HEADS 16
#define HDIM  64
#define BATCH 2
#define SEQ   2048
#define MTOT  (BATCH*SEQ)

typedef __attribute__((ext_vector_type(8)))  short short8;   // 8 bf16 = 4 VGPRs
typedef __attribute__((ext_vector_type(4)))  float f32x4;    // 16x16 C/D frag
typedef __attribute__((ext_vector_type(16))) float f32x16;   // 32x32 C/D frag

typedef __attribute__((address_space(1))) const unsigned int* gas_u32p;
typedef __attribute__((address_space(3))) unsigned int* las_u32p;

// async global->LDS, 16B per lane; LDS dest = wave-uniform base + lane*16
static __device__ __forceinline__ void gload_lds16(const void* g, void* l) {
    __builtin_amdgcn_global_load_lds((gas_u32p)g, (las_u32p)l, 16, 0, 0);
}

// fp32 -> bf16 round-to-nearest-even
static __device__ __forceinline__ unsigned short f2bf(float x) {
    unsigned u = __builtin_bit_cast(unsigned, x);
    unsigned r = (u + 0x7FFFu + ((u >> 16) & 1u)) >> 16;
    return (unsigned short)r;
}

// pack two fp32 -> one u32 of 2 bf16 (hardware cvt)
static __device__ __forceinline__ unsigned pk_bf16(float lo, float hi) {
    unsigned r;
    asm("v_cvt_pk_bf16_f32 %0, %1, %2" : "=v"(r) : "v"(lo), "v"(hi));
    return r;
}

// swap: a' = {a.lo-lanes | b.lo-lanes}, b' = {a.hi-lanes | b.hi-lanes}
static __device__ __forceinline__ void plane32_swap(unsigned &a, unsigned &b) {
    auto r = __builtin_amdgcn_permlane32_swap((int)a, (int)b, false, false);
    a = (unsigned)r[0];
    b = (unsigned)r[1];
}

static __device__ __forceinline__ f32x16 mfma32(short8 a, short8 b, f32x16 c) {
    return __builtin_amdgcn_mfma_f32_32x32x16_bf16(a, b, c, 0, 0, 0);
}

// ---------------------------------------------------------------------------
// conv_all: x (4M elems) then Wq|Wk|Wv|Wo (4x1M elems) fp32 -> bf16,
// 8 elems/thread. Block-uniform branch (2048-elem blocks never straddle
// region boundaries). Replaces convx + convw (one launch saved).
// ---------------------------------------------------------------------------
__global__ __launch_bounds__(256)
void conv_all(const float* __restrict__ x,
              const float* __restrict__ Wq, const float* __restrict__ Wk,
              const float* __restrict__ Wv, const float* __restrict__ Wo,
              unsigned short* __restrict__ xh, unsigned short* __restrict__ Wh)
{
    const size_t i = ((size_t)blockIdx.x * 256 + threadIdx.x) * 8;
    const size_t XTOT = (size_t)MTOT * EMBED;           // 4M
    const float* src;
    unsigned short* dst;
    size_t off;
    if (i < XTOT) {
        src = x; dst = xh; off = i;
    } else {
        size_t j = i - XTOT;
        int sel = (int)(j >> 20);                       // per-1M matrix select
        off = j & ((1u << 20) - 1);
        src = sel == 0 ? Wq : sel == 1 ? Wk : sel == 2 ? Wv : Wo;
        dst = Wh + ((size_t)sel << 20);
    }
    float4 a = *(const float4*)(src + off);
    float4 b = *(const float4*)(src + off + 4);
    unsigned short o[8] __attribute__((aligned(16)));
    o[0] = f2bf(a.x); o[1] = f2bf(a.y); o[2] = f2bf(a.z); o[3] = f2bf(a.w);
    o[4] = f2bf(b.x); o[5] = f2bf(b.y); o[6] = f2bf(b.z); o[7] = f2bf(b.w);
    *(uint4*)(dst + off) = *(const uint4*)o;
}

// ---------------------------------------------------------------------------
// Fused QKV GEMM (bf16 MFMA): R7 single-buffer structure (proven 55.5us),
// ONE change: BK=64 (halves barrier-drain count, doubles MFMA per drain).
// BK=64 row-major LDS would be a 16-way bank conflict (128B row stride), so
// tiles use the R10/flash-proven source-XOR swizzle: LDS[row][ch] holds
// source chunk ch^(row&7); reads XOR the same key -> ~2-way (free), global
// coalescing intact (rule #21 both-sides). Same k-permutation on A and B
// frags -> exact dot product. V written transposed to Vt[b][h][d][s];
// Q pre-scaled by 0.125*log2(e).
// ---------------------------------------------------------------------------
__global__ __launch_bounds__(256)
void gemm_qkv_bf16(const unsigned short* __restrict__ A,
                   const unsigned short* __restrict__ Wqh,
                   const unsigned short* __restrict__ Wkh,
                   const unsigned short* __restrict__ Wvh,
                   const float* __restrict__ bq,
                   const float* __restrict__ bk,
                   const float* __restrict__ bv,
                   unsigned short* __restrict__ Qb,
                   unsigned short* __restrict__ Kb,
                   unsigned short* __restrict__ Vt)
{
    __shared__ short As[128 * 64];   // 16KB, [row][chunk] with XOR'd content
    __shared__ short Bs[128 * 64];   // 16KB

    const int tid  = threadIdx.x;
    const int lane = tid & 63;
    const int w    = tid >> 6;
    const int c    = lane & 15;
    const int g    = lane >> 4;
    const int wr   = w >> 1;
    const int wc   = w & 1;

    const int m0   = blockIdx.y * 128;
    const int bxn  = blockIdx.x;
    const int wsel = bxn >> 3;
    const int n0   = (bxn & 7) * 128;

    const unsigned short* W = (wsel == 0) ? Wqh : (wsel == 1) ? Wkh : Wvh;
    const float* bias       = (wsel == 0) ? bq  : (wsel == 1) ? bk  : bv;

    f32x4 acc[4][4] = {};

    for (int k0 = 0; k0 < EMBED; k0 += 64) {
        __syncthreads();                       // prev-iter LDS reads complete
        #pragma unroll
        for (int i = 0; i < 4; ++i) {
            const int slot = w * 256 + i * 64 + lane;       // 0..1023
            const int row  = slot >> 3;
            const int chs  = (slot & 7) ^ (row & 7);        // pre-XOR'd source
            gload_lds16(A + (size_t)(m0 + row) * EMBED + k0 + chs * 8,
                        As + (size_t)(w * 256 + i * 64) * 8);
            gload_lds16(W + (size_t)(n0 + row) * EMBED + k0 + chs * 8,
                        Bs + (size_t)(w * 256 + i * 64) * 8);
        }
        __syncthreads();                       // drains vmcnt(0): tile ready

        #pragma unroll
        for (int ks = 0; ks < 2; ++ks) {       // two K=32 halves of the tile
            short8 af[4], bf[4];
            #pragma unroll
            for (int mi = 0; mi < 4; ++mi) {
                const int row = wr * 64 + mi * 16 + c;
                const int chn = (ks * 4 + g) ^ (row & 7);
                af[mi] = *(const short8*)&As[row * 64 + chn * 8];
            }
            #pragma unroll
            for (int ni = 0; ni < 4; ++ni) {
                const int row = wc * 64 + ni * 16 + c;
                const int chn = (ks * 4 + g) ^ (row & 7);
                bf[ni] = *(const short8*)&Bs[row * 64 + chn * 8];
            }
            #pragma unroll
            for (int mi = 0; mi < 4; ++mi)
                #pragma unroll
                for (int ni = 0; ni < 4; ++ni)
                    acc[mi][ni] = __builtin_amdgcn_mfma_f32_16x16x32_bf16(
                        af[mi], bf[ni], acc[mi][ni], 0, 0, 0);
        }
    }

    if (wsel == 2) {
        #pragma unroll
        for (int mi = 0; mi < 4; ++mi) {
            const int m  = m0 + wr * 64 + mi * 16 + g * 4;
            const int bb = m >> 11;
            const int ss = m & (SEQ - 1);
            #pragma unroll
            for (int ni = 0; ni < 4; ++ni) {
                const int col = n0 + wc * 64 + ni * 16 + c;
                const int hh = col >> 6, dd = col & 63;
                const float bi_ = bias[col];
                ushort4 o;
                o.x = f2bf(acc[mi][ni][0] + bi_);
                o.y = f2bf(acc[mi][ni][1] + bi_);
                o.z = f2bf(acc[mi][ni][2] + bi_);
                o.w = f2bf(acc[mi][ni][3] + bi_);
                *(ushort4*)&Vt[((size_t)((bb * HEADS + hh) * HDIM) + dd) * SEQ + ss] = o;
            }
        }
    } else {
        unsigned short* Out = (wsel == 0) ? Qb : Kb;
        // Q scale folds softmax 1/8 AND log2(e) so flash uses exp2 directly
        const float oscale  = (wsel == 0) ? 0.180336880f : 1.0f;
        #pragma unroll
        for (int mi = 0; mi < 4; ++mi)
            #pragma unroll
            for (int r = 0; r < 4; ++r) {
                const int m = m0 + wr * 64 + mi * 16 + g * 4 + r;
                #pragma unroll
                for (int ni = 0; ni < 4; ++ni) {
                    const int col = n0 + wc * 64 + ni * 16 + c;
                    Out[(size_t)m * EMBED + col] =
                        f2bf((acc[mi][ni][r] + bias[col]) * oscale);
                }
            }
    }
}

// ---------------------------------------------------------------------------
// Output GEMM: R7-proven single-buffer, BM=BN=128 (unchanged).
// ---------------------------------------------------------------------------
__global__ __launch_bounds__(256)
void gemm_o_bf16(const unsigned short* __restrict__ A,
                 const unsigned short* __restrict__ Woh,
                 const float* __restrict__ bo,
                 float* __restrict__ C)
{
    __shared__ short As[128 * 32];
    __shared__ short Bs[128 * 32];

    const int tid  = threadIdx.x;
    const int lane = tid & 63;
    const int w    = tid >> 6;
    const int c    = lane & 15;
    const int g    = lane >> 4;
    const int wr   = w >> 1;
    const int wc   = w & 1;

    const int m0 = blockIdx.y * 128;
    const int n0 = blockIdx.x * 128;

    f32x4 acc[4][4] = {};

    for (int k0 = 0; k0 < EMBED; k0 += 32) {
        __syncthreads();
        #pragma unroll
        for (int i = 0; i < 2; ++i) {
            int s   = (w * 2 + i) * 64 + lane;
            int row = s >> 2;
            int k8  = (s & 3) * 8;
            gload_lds16(A + (size_t)(m0 + row) * EMBED + k0 + k8,
                        As + (size_t)(w * 2 + i) * 512);
            gload_lds16(Woh + (size_t)(n0 + row) * EMBED + k0 + k8,
                        Bs + (size_t)(w * 2 + i) * 512);
        }
        __syncthreads();

        short8 af[4], bf[4];
        #pragma unroll
        for (int mi = 0; mi < 4; ++mi)
            af[mi] = *(const short8*)&As[(wr * 64 + mi * 16 + c) * 32 + g * 8];
        #pragma unroll
        for (int ni = 0; ni < 4; ++ni)
            bf[ni] = *(const short8*)&Bs[(wc * 64 + ni * 16 + c) * 32 + g * 8];
        #pragma unroll
        for (int mi = 0; mi < 4; ++mi)
            #pragma unroll
            for (int ni = 0; ni < 4; ++ni)
                acc[mi][ni] = __builtin_amdgcn_mfma_f32_16x16x32_bf16(
                    af[mi], bf[ni], acc[mi][ni], 0, 0, 0);
    }

    #pragma unroll
    for (int mi = 0; mi < 4; ++mi)
        #pragma unroll
        for (int r = 0; r < 4; ++r) {
            const int m = m0 + wr * 64 + mi * 16 + g * 4 + r;
            #pragma unroll
            for (int ni = 0; ni < 4; ++ni) {
                const int col = n0 + wc * 64 + ni * 16 + c;
                C[(size_t)m * EMBED + col] = acc[mi][ni][r] + bo[col];
            }
        }
}

// ---------------------------------------------------------------------------
// MFMA flash attention v5 (unchanged; proven):
// fixed-base softmax via exp2, in-register P, kv-split-2, 2-phase staging.
// ---------------------------------------------------------------------------
__global__ __launch_bounds__(512, 4)
void flash_attn_mfma5(const unsigned short* __restrict__ Qb,
                      const unsigned short* __restrict__ Kb,
                      const unsigned short* __restrict__ Vt,
                      unsigned short* __restrict__ O)
{
    __shared__ short KT[2][2][64 * 64];   // [half][buf][kv][d]  (swizzled chunks)
    __shared__ short VT[2][2][64 * 64];   // [half][buf][d][kv]

    const int tid  = threadIdx.x;
    const int lane = tid & 63;
    const int w    = tid >> 6;            // 0..7
    const int qt   = w & 3;               // q subtile
    const int half = w >> 2;              // kv half
    const int l31  = lane & 31;
    const int hi   = lane >> 5;
    const int q0   = blockIdx.x * 128 + qt * 32;
    const int h    = blockIdx.y;
    const int b    = blockIdx.z;

    // persistent Q B-frags: qf[kc] holds Q[q=l31][d = kc*16 + hi*8 + j]
    short8 qf[4];
    {
        const unsigned short* qrow =
            Qb + (size_t)(b * SEQ + q0 + l31) * EMBED + h * HDIM + hi * 8;
        #pragma unroll
        for (int kc = 0; kc < 4; ++kc)
            qf[kc] = *(const short8*)(qrow + kc * 16);
    }

    // staging: tile tb = w>>1 (0=K_lo,1=V_lo,2=K_hi,3=V_hi), ssub = w&1.
    const int tb     = w >> 1;
    const int sthalf = tb >> 1;
    const int stV    = tb & 1;
    const int ssub   = w & 1;
    const int strow  = ssub * 32 + (lane >> 3);
    const int ch     = (lane & 7) ^ (strow & 7);
    const unsigned short* kS =
        Kb + (size_t)(b * SEQ + sthalf * (SEQ / 2) + strow) * EMBED + h * HDIM + ch * 8;
    const unsigned short* vS =
        Vt + ((size_t)((b * HEADS + h) * HDIM) + strow) * SEQ + sthalf * (SEQ / 2) + ch * 8;

    f32x16 acc[2] = {};
    float l_run = 0.f;

    #define STAGE(kt2, bb)                                                    \
        do {                                                                  \
            if (stV == 0) {                                                   \
                const unsigned short* src = kS + (size_t)(kt2) * 64 * EMBED;  \
                short* kd = &KT[sthalf][bb][ssub * 2048];                     \
                _Pragma("unroll")                                             \
                for (int it = 0; it < 4; ++it)                                \
                    gload_lds16(src + (size_t)it * 8 * EMBED, kd + it * 512); \
            } else {                                                          \
                const unsigned short* src = vS + (kt2) * 64;                  \
                short* vd = &VT[sthalf][bb][ssub * 2048];                     \
                _Pragma("unroll")                                             \
                for (int it = 0; it < 4; ++it)                                \
                    gload_lds16(src + (size_t)it * 8 * SEQ, vd + it * 512);   \
            }                                                                 \
        } while (0)

    STAGE(0, 0);
    __syncthreads();

    for (int kt = 0; kt < SEQ / 2 / 64; ++kt) {
        const int bi = kt & 1;
        if (kt < SEQ / 2 / 64 - 1) STAGE(kt + 1, bi ^ 1);

        const short* kb_ = &KT[half][bi][0];
        const short* vb_ = &VT[half][bi][0];

        // ---- QK^T (C: col=l31=q, row=kv via qr formula)
        f32x16 s[2] = {};
        __builtin_amdgcn_s_setprio(1);
        #pragma unroll
        for (int t = 0; t < 2; ++t) {
            const int row = t * 32 + l31;
            const int rm  = l31 & 7;
            #pragma unroll
            for (int kc = 0; kc < 4; ++kc) {
                short8 ka = *(const short8*)&kb_[row * 64 + (((2 * kc + hi) ^ rm) * 8)];
                s[t] = mfma32(ka, qf[kc], s[t]);
            }
        }
        __builtin_amdgcn_s_setprio(0);

        // ---- P = exp2(s'), row-sum (fixed-base softmax: no max machinery)
        float rs = 0.f;
        #pragma unroll
        for (int t = 0; t < 2; ++t)
            #pragma unroll
            for (int r = 0; r < 16; ++r) {
                float pv = __builtin_amdgcn_exp2f(s[t][r]);
                s[t][r] = pv;
                rs += pv;
            }
        rs += __shfl_xor(rs, 32, 64);
        l_run += rs;

        // ---- P -> A-frags in-register (cvt_pk + permlane32_swap)
        short8 pf[2][2];
        #pragma unroll
        for (int t = 0; t < 2; ++t)
            #pragma unroll
            for (int kc = 0; kc < 2; ++kc) {
                unsigned A0 = pk_bf16(s[t][8 * kc + 0], s[t][8 * kc + 1]);
                unsigned A1 = pk_bf16(s[t][8 * kc + 2], s[t][8 * kc + 3]);
                unsigned B0 = pk_bf16(s[t][8 * kc + 4], s[t][8 * kc + 5]);
                unsigned B1 = pk_bf16(s[t][8 * kc + 6], s[t][8 * kc + 7]);
                plane32_swap(A0, B0);
                plane32_swap(A1, B1);
                uint4 fw = make_uint4(A0, A1, B0, B1);
                pf[t][kc] = __builtin_bit_cast(short8, fw);
            }

        // ---- PV
        __builtin_amdgcn_s_setprio(1);
        #pragma unroll
        for (int dt = 0; dt < 2; ++dt) {
            const int row = dt * 32 + l31;
            const int rm  = l31 & 7;
            #pragma unroll
            for (int t = 0; t < 2; ++t)
                #pragma unroll
                for (int kc = 0; kc < 2; ++kc) {
                    short8 vf = *(const short8*)
                        &vb_[row * 64 + (((4 * t + 2 * kc + hi) ^ rm) * 8)];
                    acc[dt] = mfma32(pf[t][kc], vf, acc[dt]);
                }
        }
        __builtin_amdgcn_s_setprio(0);

        __syncthreads();
    }
    #undef STAGE

    // ---- merge kv-halves: O = (O_lo + O_hi) / (l_lo + l_hi)  (exact fp32)
    float* mrgf = (float*)&KT[0][0][0];   // 4 pairs x 32q x 64d fp32 = 32KB
    float* mlbf = (float*)&VT[0][0][0];   // 4 pairs x 32q l-values
    if (half == 1) {
        #pragma unroll
        for (int dt = 0; dt < 2; ++dt)
            #pragma unroll
            for (int r = 0; r < 16; ++r) {
                const int qr = (r & 3) + 8 * (r >> 2) + 4 * hi;
                mrgf[qt * 2048 + qr * 64 + dt * 32 + l31] = acc[dt][r];
            }
        if (lane < 32)
            mlbf[qt * 32 + lane] = l_run;
    }
    __syncthreads();
    if (half == 0) {
        const float lo  = mlbf[qt * 32 + l31];
        const float inv = 1.f / (l_run + lo);
        #pragma unroll
        for (int r = 0; r < 16; ++r) {
            const int qr = (r & 3) + 8 * (r >> 2) + 4 * hi;
            float invr = __shfl(inv, qr, 64);
            #pragma unroll
            for (int dt = 0; dt < 2; ++dt) {
                float oh  = mrgf[qt * 2048 + qr * 64 + dt * 32 + l31];
                float val = (acc[dt][r] + oh) * invr;
                O[(size_t)(b * SEQ + q0 + qr) * EMBED + h * HDIM + dt * 32 + l31]
                    = f2bf(val);
            }
        }
    }
}

// ---------------------------------------------------------------------------
extern "C" void kernel_launch(void* const* d_in, const int* in_sizes, int n_in,
                              void* d_out, int out_size, void* d_ws, size_t ws_size,
                              hipStream_t stream)
{
    const float* x  = (const float*)d_in[0];
    const float* Wq = (const float*)d_in[1];
    const float* bq = (const float*)d_in[2];
    const float* Wk = (const float*)d_in[3];
    const float* bk = (const float*)d_in[4];
    const float* Wv = (const float*)d_in[5];
    const float* bv = (const float*)d_in[6];
    const float* Wo = (const float*)d_in[7];
    const float* bo = (const float*)d_in[8];
    float* out = (float*)d_out;

    const size_t ME = (size_t)MTOT * EMBED;
    unsigned short* xh   = (unsigned short*)d_ws;     // 8 MB each
    unsigned short* Qb   = xh   + ME;
    unsigned short* Kb   = Qb   + ME;
    unsigned short* Vt   = Kb   + ME;                 // [b][h][d][s]
    unsigned short* attn = Vt   + ME;
    unsigned short* Wh   = attn + ME;                 // 4 x 2 MB packed

    dim3 blk(256);

    // 8M elems total (x 4M + W 4M), 2048 elems/block
    conv_all<<<dim3((2 * ME) / 2048), blk, 0, stream>>>(x, Wq, Wk, Wv, Wo, xh, Wh);

    gemm_qkv_bf16<<<dim3(24, MTOT / 128), blk, 0, stream>>>(
        xh, Wh, Wh + (size_t)EMBED * EMBED, Wh + 2 * (size_t)EMBED * EMBED,
        bq, bk, bv, Qb, Kb, Vt);

    flash_attn_mfma5<<<dim3(SEQ / 128, HEADS, BATCH), dim3(512), 0, stream>>>(
        Qb, Kb, Vt, attn);

    gemm_o_bf16<<<dim3(EMBED / 128, MTOT / 128), blk, 0, stream>>>(
        attn, Wh + 3 * (size_t)EMBED * EMBED, bo, out);
}